// Round 7
// baseline (103.903 us; speedup 1.0000x reference)
//
#include <hip/hip_runtime.h>
#include <math.h>

// LRU (Laguerre ladder) recurrence, MI355X.
// B=32, T=512, I=64, F=64, H=64. Output: (B,T,F,H) f32 ++ h_final (F,B,H) f32.
// One wave = 4 chains (b, f0..f0+3): lane l = (g=l>>4, j=l&15) owns h=4j..4j+3
// of chain f0+g. Wavefront-skew over t within each 16-lane group: lane j
// computes row t = k - j at step k (skew span 16).
// Ring: 48 slots x 1KB ([4f][64h] per t) = 48KB; +u 8.75KB -> 2 blocks/CU,
// grid 512 = exactly one resident cohort.
// Flush: 16-row chunks; chunk q ds_read at k=16q+38 (complete at 16q+30, slot
// reuse at 16q+48; same-wave in-order DS -> race-free, no barriers), stored
// 16 STEPs later (ping-pong gA/gB) as 16x 1KB-contiguous global_store_dwordx4.
#define TT 512
#define FF 64
#define BB 32
#define HH 64
#define NSLOT 48
#define US 560                      // u row stride per chain (floats)

// lane j in each 16-lane row gets lane j-1's value; j==0 gets 0 (bound_ctrl)
__device__ __forceinline__ float dpp_row_shr1(float v) {
    int r = __builtin_amdgcn_update_dpp(0, __float_as_int(v), 0x111, 0xf, 0xf, true);
    return __int_as_float(r);
}

// one recurrence step over 4 hidden indices; MASKED is a compile-time literal
#define STEP(MASKED) do {                                              \
    const float uk_ = *up_; ++up_;                                     \
    const float shifted_ = dpp_row_shr1(v3);                           \
    const float nbr_cur_ = isj0 ? uk_ : shifted_;                      \
    float n0_ = fmaf(cA, nbr_cur_, fmaf(a, prev0, -nbr_prev));         \
    float n1_ = fmaf(a, n0_, fmaf(a, prev1, -prev0));                  \
    float n2_ = fmaf(a, n1_, fmaf(a, prev2, -prev1));                  \
    float n3_ = fmaf(a, n2_, fmaf(a, prev3, -prev2));                  \
    if (MASKED) {                                                      \
        const bool live_ = ((unsigned)t < (unsigned)TT);               \
        n0_ = live_ ? n0_ : prev0;                                     \
        n1_ = live_ ? n1_ : prev1;                                     \
        n2_ = live_ ? n2_ : prev2;                                     \
        n3_ = live_ ? n3_ : prev3;                                     \
        if (live_) {                                                   \
            float4 w4_; w4_.x=n0_; w4_.y=n1_; w4_.z=n2_; w4_.w=n3_;    \
            *(float4*)((char*)ring + vaddr) = w4_;                     \
        }                                                              \
    } else {                                                           \
        float4 w4_; w4_.x=n0_; w4_.y=n1_; w4_.z=n2_; w4_.w=n3_;        \
        *(float4*)((char*)ring + vaddr) = w4_;                         \
    }                                                                  \
    vaddr += 1024; vaddr = (vaddr == vtop) ? vbase : vaddr;            \
    nbr_prev = isj0 ? 0.f : nbr_cur_;                                  \
    prev0 = n0_; prev1 = n1_; prev2 = n2_; prev3 = n3_; v3 = n3_;      \
    ++t;                                                               \
} while (0)

// read next chunk (16 t-rows x 1KB) into GARR; capture its out ptr
#define READS(GARR, OPP) do {                                          \
    const char* rp_ = (const char*)ring + sb * 1024 + (l << 4);        \
    _Pragma("unroll")                                                  \
    for (int i_ = 0; i_ < 16; ++i_)                                    \
        GARR[i_] = *(const float4*)(rp_ + i_ * 1024);                  \
    OPP = ochunk + (l << 2);                                           \
    ochunk += 16 * 4096;                                               \
    sb += 16; if (sb == NSLOT) sb = 0;                                 \
} while (0)

// store i covers out row t0+i: 1KB contiguous [f0..f0+3][0..63], lane l -> floats 4l..4l+3
#define STORES(GARR, OPP) do {                                         \
    _Pragma("unroll")                                                  \
    for (int i_ = 0; i_ < 16; ++i_)                                    \
        *(float4*)(OPP + (size_t)i_ * 4096) = GARR[i_];                \
} while (0)

#define PT_RD_A do { READS(gA, opA); } while (0)
#define PT_AB   do { STORES(gA, opA); READS(gB, opB); } while (0)
#define PT_BA   do { STORES(gB, opB); READS(gA, opA); } while (0)
#define NOPT    do {} while (0)

// one 32-STEP half; flush points after STEP i_=6 and i_=22 (k = 16q+38 pattern)
#define HALF(MASKED, P6, P22) do {                                     \
    _Pragma("unroll")                                                  \
    for (int i_ = 0; i_ < 32; ++i_) {                                  \
        STEP(MASKED);                                                  \
        if (i_ == 6)  { P6; }                                          \
        if (i_ == 22) { P22; }                                         \
    }                                                                  \
} while (0)

__global__ __launch_bounds__(64) void lru_kernel(
    const float* __restrict__ x,      // (B,T,I)
    const float* __restrict__ W,      // (F,I)
    const float* __restrict__ relax,  // (F,)
    float* __restrict__ out)          // (B,T,F,H) ++ (F,B,H)
{
    __shared__ float u_lds[4 * US];       // 8960 B
    __shared__ float ring[NSLOT * 256];   // 49152 B; row t: [4f][64h]

    const int w  = blockIdx.x;            // 512 blocks: (b, f-group)
    const int b  = w >> 4;
    const int f0 = (w & 15) << 2;
    const int l  = threadIdx.x;
    const int j  = l & 15;                // position in chain (h = 4j..4j+3)
    const int g  = l >> 4;                // chain 0..3 (f = f0+g)

    // ---------- phase 1: u[g][t] = dot(x[b,t,:], W[f0+g,:]) (r1-verified) ----------
    {
        const float4* __restrict__ Wv = reinterpret_cast<const float4*>(W) + (size_t)f0 * 16;
        #pragma unroll
        for (int c = 0; c < 8; ++c) {
            const int tt = (c << 6) + l;  // each lane one t, all 4 chains
            const float4* xv = reinterpret_cast<const float4*>(x) + ((size_t)b * TT + tt) * 16;
            float a0 = 0.f, a1 = 0.f, a2 = 0.f, a3 = 0.f;
            #pragma unroll
            for (int q = 0; q < 16; ++q) {
                const float4 xq = xv[q];
                const float4 w0 = Wv[q];
                const float4 w1 = Wv[16 + q];
                const float4 w2 = Wv[32 + q];
                const float4 w3 = Wv[48 + q];
                a0 = fmaf(xq.x, w0.x, fmaf(xq.y, w0.y, fmaf(xq.z, w0.z, fmaf(xq.w, w0.w, a0))));
                a1 = fmaf(xq.x, w1.x, fmaf(xq.y, w1.y, fmaf(xq.z, w1.z, fmaf(xq.w, w1.w, a1))));
                a2 = fmaf(xq.x, w2.x, fmaf(xq.y, w2.y, fmaf(xq.z, w2.z, fmaf(xq.w, w2.w, a2))));
                a3 = fmaf(xq.x, w3.x, fmaf(xq.y, w3.y, fmaf(xq.z, w3.z, fmaf(xq.w, w3.w, a3))));
            }
            u_lds[0 * US + tt] = a0;
            u_lds[1 * US + tt] = a1;
            u_lds[2 * US + tt] = a2;
            u_lds[3 * US + tt] = a3;
        }
        // zero the tail u[512..559] so masked ramp-out steps read finite values
        if (l < US - TT) {
            u_lds[0 * US + TT + l] = 0.f;
            u_lds[1 * US + TT + l] = 0.f;
            u_lds[2 * US + TT + l] = 0.f;
            u_lds[3 * US + TT + l] = 0.f;
        }
    }
    // single wave: same-wave in-order DS, no barrier needed

    // ---------- phase 2: skewed recurrence ----------
    const float rel = relax[f0 + g];
    const float a  = sqrtf(rel);
    const float gn = sqrtf(1.0f - rel);
    const bool isj0 = (j == 0);
    const float cA = isj0 ? gn : a;

    float prev0 = 0.f, prev1 = 0.f, prev2 = 0.f, prev3 = 0.f;
    float nbr_prev = 0.f, v3 = 0.f;
    int t = -j;                            // lane's timestep; ++ every STEP

    const int vbase = g * 256 + (j << 4);  // byte offset within a ring row
    const int vtop  = NSLOT * 1024 + vbase;
    int vaddr = ((NSLOT - j) % NSLOT) * 1024 + vbase;   // slot (t mod 48)

    const float* up_ = u_lds + g * US;     // u[g][k], consumed only by j==0

    int sb = 0;                            // ring slot base of next chunk to read
    float* ochunk = out + (size_t)b * (TT * FF * HH) + (size_t)f0 * HH;
    float4 gA[16], gB[16];
    float *opA = nullptr, *opB = nullptr;

    // h=0 (k=0..31): masked ramp-in, ring fills
    HALF(true, NOPT, NOPT);
    // h=1 (k=32..63): p0@k=38 reads chunk0->A; p1@k=54 stores c0, reads c1->B
    HALF(false, PT_RD_A, PT_AB);
    // h=2..15 (k=64..511): steady; every half = (store B read A, store A read B)
    #pragma unroll 1
    for (int h = 2; h <= 15; ++h) {
        HALF(false, PT_BA, PT_AB);
    }
    // h=16 (k=512..543): masked ramp-out; flushes chunks 30,31
    HALF(true, PT_BA, PT_AB);
    // chunk 31 sits in B
    STORES(gB, opB);

    // h_final = y[T-1] (frozen in prev0..3)
    float4 hf; hf.x = prev0; hf.y = prev1; hf.z = prev2; hf.w = prev3;
    *(float4*)(out + (size_t)BB * TT * FF * HH
                   + ((size_t)(f0 + g) * BB + b) * HH + (j << 2)) = hf;
}

extern "C" void kernel_launch(void* const* d_in, const int* in_sizes, int n_in,
                              void* d_out, int out_size, void* d_ws, size_t ws_size,
                              hipStream_t stream) {
    const float* x     = (const float*)d_in[0];
    const float* W     = (const float*)d_in[1];
    const float* relax = (const float*)d_in[2];
    float* out = (float*)d_out;
    lru_kernel<<<dim3(512), dim3(64), 0, stream>>>(x, W, relax, out);
}